// Round 5
// baseline (870.928 us; speedup 1.0000x reference)
//
#include <hip/hip_runtime.h>
#include <hip/hip_bf16.h>

typedef __attribute__((ext_vector_type(8))) short bf16x8;
typedef __attribute__((ext_vector_type(4))) float f32x4;

#define HD 256   // hidden size (K of the big GEMM)
#define NB 32    // batch
#define NT 4096  // timesteps
#define NE 8192  // edges per graph
#define N2 512   // 2*H (N of the big GEMM)

static __device__ __forceinline__ unsigned short f2bf(float f) {
  unsigned int u = __float_as_uint(f);
  u += 0x7fff + ((u >> 16) & 1);  // round-to-nearest-even
  return (unsigned short)(u >> 16);
}
static __device__ __forceinline__ short4 cvt4(float4 a) {
  return make_short4((short)f2bf(a.x), (short)f2bf(a.y),
                     (short)f2bf(a.z), (short)f2bf(a.w));
}
// tanh(x) = 1 - 2/(e^{2x}+1); e^{2x} via exp2. Saturates correctly at +-inf.
static __device__ __forceinline__ float fast_tanh(float x) {
  float e = __builtin_amdgcn_exp2f(x * 2.8853900817779268f);  // 2/ln2
  return __builtin_fmaf(-2.f, __builtin_amdgcn_rcpf(e + 1.f), 1.f);
}
// pack 8 fp32 (k-ascending) -> bf16x8 by truncation (validated R9)
static __device__ __forceinline__ bf16x8 pack8(float4 a, float4 b) {
  union { bf16x8 v; unsigned int u[4]; } r;
  r.u[0] = (__float_as_uint(a.y) & 0xffff0000u) | (__float_as_uint(a.x) >> 16);
  r.u[1] = (__float_as_uint(a.w) & 0xffff0000u) | (__float_as_uint(a.z) >> 16);
  r.u[2] = (__float_as_uint(b.y) & 0xffff0000u) | (__float_as_uint(b.x) >> 16);
  r.u[3] = (__float_as_uint(b.w) & 0xffff0000u) | (__float_as_uint(b.z) >> 16);
  return r.v;
}

// Fused prep:
//  blocks 0..255   : cvecT[n][b] = b_attn[n] + hidden[b] . W_attn[n][0:256]
//  blocks 256..383 : WbfT k-block-major bf16 convert of W_attn[n][256+k]:
//                    WbfT[((k>>5)*512 + n)*32 + (k&31)] = bf16(W2[n][k])
__global__ __launch_bounds__(256) void prep(
    const float* __restrict__ hidden, const float* __restrict__ Wattn,
    const float* __restrict__ battn, float* __restrict__ cvecT,
    short* __restrict__ WbfT) {
  const int tid = threadIdx.x;
  if (blockIdx.x < 256) {
    __shared__ float Ws[64 * 260];
    __shared__ float Hs[HD];
    const int chunk = blockIdx.x & 7;
    const int b = blockIdx.x >> 3;
#pragma unroll
    for (int it = 0; it < 16; ++it) {
      int f = it * 1024 + tid * 4;
      int i = f >> 8, k = f & 255;
      float4 w4 = *(const float4*)(Wattn + (chunk * 64 + i) * N2 + k);
      *(float4*)&Ws[i * 260 + k] = w4;
    }
    if (tid < 64)
      *(float4*)&Hs[tid * 4] = *(const float4*)(hidden + b * HD + tid * 4);
    __syncthreads();
    const int nl = tid >> 2;
    const int kb = (tid & 3) * 64;
    float sum = 0.f;
#pragma unroll
    for (int z = 0; z < 64; z += 4) {
      float4 h4 = *(const float4*)&Hs[kb + z];
      float4 w4 = *(const float4*)&Ws[nl * 260 + kb + z];
      sum = fmaf(h4.x, w4.x, sum);
      sum = fmaf(h4.y, w4.y, sum);
      sum = fmaf(h4.z, w4.z, sum);
      sum = fmaf(h4.w, w4.w, sum);
    }
    sum += __shfl_xor(sum, 1, 64);
    sum += __shfl_xor(sum, 2, 64);
    if ((tid & 3) == 0)
      cvecT[(chunk * 64 + nl) * NB + b] = sum + battn[chunk * 64 + nl];
  } else {
    int f = (blockIdx.x - 256) * 1024 + tid * 4;  // 0..131071 = n*256+k
    int n = f >> 8, k = f & 255;                  // k multiple of 4
    float4 w4 = *(const float4*)(Wattn + n * N2 + HD + k);
    *(short4*)(WbfT + ((k >> 5) * 512 + n) * 32 + (k & 31)) = cvt4(w4);
  }
}

// Load one K-step's B fragments (4 x bf16x8). Coalesced: contiguous 1KB/wave.
static __device__ __forceinline__ void bload(bf16x8* dst, const short* __restrict__ Wp,
                                             int nbase, int q, int kk) {
  const short* base = Wp + (kk * 512 + nbase) * 32 + q * 8;
#pragma unroll
  for (int nf = 0; nf < 4; ++nf)
    dst[nf] = *(const bf16x8*)(base + nf * 16 * 32);
}

// One K-step (BK=32): 4 A-frag bf16 ds_reads + 16 MFMAs against held B frags.
static __device__ __forceinline__ void kstep(f32x4 acc[4][4], const short* Abf,
                                             const bf16x8* b, int rb, int m, int q,
                                             int ks) {
#pragma unroll
  for (int mi = 0; mi < 4; ++mi) {
    const int r = rb + mi * 16 + m;
    const int cc = ks * 4 + q;
    const int slot = (cc & ~7) | ((cc & 7) ^ (r & 7));
    bf16x8 af = *(const bf16x8*)&Abf[r * 256 + slot * 8];
#pragma unroll
    for (int nf = 0; nf < 4; ++nf)
      acc[mi][nf] =
          __builtin_amdgcn_mfma_f32_16x16x32_bf16(af, b[nf], acc[mi][nf], 0, 0, 0);
  }
}

// ---------------------------------------------------------------------------
// ABLATION PROBE (perf-diagnostic; output never observed): exact R3 score_gemm
// with ONLY the global A(enc) loads replaced by synthesized register values.
// Staging ds_writes, barriers, coalesced B loads, ds_reads, MFMAs and the tanh
// epilogue are all real, repeated REPS=8x per block. Liveness is anchored by a
// value-guarded store into scores[] (practically never taken; scores is fully
// overwritten by the real score_gemm afterwards, so correctness is unaffected).
// Reading: dur >= ~700us -> A-stream innocent (kernel internally bound);
//          dur <= ~450us -> A-load path is the missing ~70us of score_gemm.
// ---------------------------------------------------------------------------
__global__ __launch_bounds__(1024, 4) void probe_noA8(
    const short* __restrict__ WbfT, const float* __restrict__ cvecT,
    const float* __restrict__ vvec, float* __restrict__ scores) {
  __shared__ short Abf[128 * 256];
  __shared__ float part[16][64];
  const int tid = threadIdx.x;
  const int w = tid >> 6, lane = tid & 63, q = lane >> 4, m = lane & 15;
  const int g = w >> 3, wl = w & 7;
  const int nbase = wl * 64 + m;
  const int rb = g * 64;

  f32x4 acc[4][4];
#pragma unroll
  for (int mi = 0; mi < 4; ++mi)
#pragma unroll
    for (int nf = 0; nf < 4; ++nf) acc[mi][nf] = (f32x4){0.f, 0.f, 0.f, 0.f};

#pragma unroll 1
  for (int rep = 0; rep < 8; ++rep) {
    // ---- stage A: SAME ds_write pattern as the real kernel, values synth ----
#pragma unroll
    for (int i = 0; i < 4; ++i) {
      const int gg = i * 1024 + tid;  // 0..4095 = r*32 + c
      const int r = gg >> 5, c = gg & 31;
      const unsigned hv = (gg * 2654435761u) ^ (rep * 0x9E3779B9u);
      float4 a0, a1;
      a0.x = __uint_as_float((hv & 0x007FFFFFu) | 0x3F000000u);
      a0.y = __uint_as_float(((hv >> 3) & 0x007FFFFFu) | 0x3F000000u);
      a0.z = __uint_as_float(((hv >> 5) & 0x007FFFFFu) | 0x3F000000u);
      a0.w = __uint_as_float(((hv >> 7) & 0x007FFFFFu) | 0x3F000000u);
      a1.x = a0.w; a1.y = a0.z; a1.z = a0.y; a1.w = a0.x;
      const int slot = (c & ~7) | ((c & 7) ^ (r & 7));
      *(bf16x8*)&Abf[r * 256 + slot * 8] = pack8(a0, a1);
    }
    __syncthreads();

    // ---- K-loop: real coalesced B loads (rep-rotated k index), real MFMA ----
    bf16x8 b0[4], b1[4];
    bload(b0, WbfT, nbase, q, rep & 7);
#pragma unroll
    for (int ks2 = 0; ks2 < 4; ++ks2) {
      const int ks = ks2 * 2;
      bload(b1, WbfT, nbase, q, (ks + 1 + rep) & 7);
      kstep(acc, Abf, b0, rb, m, q, ks);
      if (ks2 < 3) bload(b0, WbfT, nbase, q, (ks + 2 + rep) & 7);
      kstep(acc, Abf, b1, rb, m, q, ks + 1);
    }

    // ---- epilogue: real tanh + v-dot + shuffles + part writes ----
    float pr[4][4];
#pragma unroll
    for (int mi = 0; mi < 4; ++mi)
#pragma unroll
      for (int j = 0; j < 4; ++j) pr[mi][j] = 0.f;
#pragma unroll
    for (int nf = 0; nf < 4; ++nf) {
      const int n = wl * 64 + nf * 16 + m;
      const float vv = vvec[n];
      const f32x4 cvA = *(const f32x4*)(cvecT + n * NB + 4 * q);
      const f32x4 cvB = *(const f32x4*)(cvecT + n * NB + 16 + 4 * q);
#pragma unroll
      for (int mi = 0; mi < 4; ++mi) {
        const f32x4 cv = (mi & 1) ? cvB : cvA;
#pragma unroll
        for (int j = 0; j < 4; ++j)
          pr[mi][j] += fast_tanh(acc[mi][nf][j] + cv[j]) * vv;
      }
    }
#pragma unroll
    for (int mi = 0; mi < 4; ++mi) {
#pragma unroll
      for (int j = 0; j < 4; ++j) {
        float e = pr[mi][j];
        e += __shfl_xor(e, 1, 64);
        e += __shfl_xor(e, 2, 64);
        e += __shfl_xor(e, 4, 64);
        e += __shfl_xor(e, 8, 64);
        if (m == 0) part[w][mi * 16 + 4 * q + j] = e;
      }
    }
    __syncthreads();
    // liveness anchor: value-guarded, practically never taken; scores is
    // fully rewritten by the real score_gemm launched after this probe.
    if (tid < 128) {
      float s = 0.f;
#pragma unroll
      for (int ww = 0; ww < 8; ++ww) s += part[(tid >> 6) * 8 + ww][tid & 63];
      if (s == 1234.5678f) scores[blockIdx.x * 128 + tid] = s;
    }
    __syncthreads();
  }
}

// B-coalesced, M128 GEMM (R3 best, 111us): block = 1024 threads (16 waves),
// 128 M-rows x 512 N. Two 8-wave M-groups share B (L1 reuse); A reg-staged
// fp32->bf16 into 64KB swizzled LDS once; K-loop barrier-free; B reg-dbuf.
__global__ __launch_bounds__(1024, 4) void score_gemm(
    const float* __restrict__ enc, const short* __restrict__ WbfT,
    const float* __restrict__ cvecT, const float* __restrict__ vvec,
    float* __restrict__ scores) {
  __shared__ short Abf[128 * 256];  // 128 rows x 256 k bf16, swizzled: 64 KB
  __shared__ float part[16][64];
  const int tid = threadIdx.x;
  const int w = tid >> 6, lane = tid & 63, q = lane >> 4, m = lane & 15;
  const int g = w >> 3, wl = w & 7;
  const int row0 = blockIdx.x * 128;

  // ---- stage ALL of A: fp32 global -> bf16 LDS (each thread 4 chunks) ----
#pragma unroll
  for (int i = 0; i < 4; ++i) {
    const int gg = i * 1024 + tid;     // 0..4095 = r*32 + c
    const int r = gg >> 5, c = gg & 31;
    const float* src = enc + (row0 + r) * HD + c * 8;
    float4 a0 = *(const float4*)src;
    float4 a1 = *(const float4*)(src + 4);
    const int slot = (c & ~7) | ((c & 7) ^ (r & 7));
    *(bf16x8*)&Abf[r * 256 + slot * 8] = pack8(a0, a1);
  }

  f32x4 acc[4][4];
#pragma unroll
  for (int mi = 0; mi < 4; ++mi)
#pragma unroll
    for (int nf = 0; nf < 4; ++nf) acc[mi][nf] = (f32x4){0.f, 0.f, 0.f, 0.f};

  const int nbase = wl * 64 + m;
  const int rb = g * 64;
  bf16x8 b0[4], b1[4];
  bload(b0, WbfT, nbase, q, 0);  // prologue B prefetch

  __syncthreads();  // the ONLY barrier: A staged, everyone may read LDS

#pragma unroll 1
  for (int ks2 = 0; ks2 < 4; ++ks2) {
    const int ks = ks2 * 2;
    bload(b1, WbfT, nbase, q, ks + 1);  // prefetch next step's B
    kstep(acc, Abf, b0, rb, m, q, ks);
    if (ks2 < 3) bload(b0, WbfT, nbase, q, ks + 2);
    kstep(acc, Abf, b1, rb, m, q, ks + 1);
  }

  // ---- epilogue: tanh + v-dot, reduce over this wave's 64 cols ----
  float p[4][4];
#pragma unroll
  for (int mi = 0; mi < 4; ++mi)
#pragma unroll
    for (int j = 0; j < 4; ++j) p[mi][j] = 0.f;

#pragma unroll
  for (int nf = 0; nf < 4; ++nf) {
    const int n = wl * 64 + nf * 16 + m;
    const float vv = vvec[n];
    // C/D layout: M-coord = rb + mi*16 + 4q+j; b-index = (mi*16+4q+j)&31
    const f32x4 cvA = *(const f32x4*)(cvecT + n * NB + 4 * q);        // mi even
    const f32x4 cvB = *(const f32x4*)(cvecT + n * NB + 16 + 4 * q);   // mi odd
#pragma unroll
    for (int mi = 0; mi < 4; ++mi) {
      const f32x4 cv = (mi & 1) ? cvB : cvA;
#pragma unroll
      for (int j = 0; j < 4; ++j)
        p[mi][j] += fast_tanh(acc[mi][nf][j] + cv[j]) * vv;
    }
  }
#pragma unroll
  for (int mi = 0; mi < 4; ++mi) {
#pragma unroll
    for (int j = 0; j < 4; ++j) {
      float e = p[mi][j];
      e += __shfl_xor(e, 1, 64);
      e += __shfl_xor(e, 2, 64);
      e += __shfl_xor(e, 4, 64);
      e += __shfl_xor(e, 8, 64);  // sum over the 16 m-lanes
      if (m == 0) part[w][mi * 16 + 4 * q + j] = e;
    }
  }
  __syncthreads();
  if (tid < 128) {
    const int r = row0 + tid;  // flat row = t*NB + b
    float s = 0.f;
#pragma unroll
    for (int ww = 0; ww < 8; ++ww) s += part[(tid >> 6) * 8 + ww][tid & 63];
    scores[(r & 31) * NT + (r >> 5)] = s;
  }
}

// Fused softmax + edge scatter: one block per batch b (1024 threads).
__global__ __launch_bounds__(1024) void softmax_scatter(
    const float* __restrict__ sc, const int* __restrict__ esrc,
    const int* __restrict__ edst, float* __restrict__ out) {
  __shared__ float wls[NT];   // 16 KB: 0.1 * softmax(sc[b])
  __shared__ float accs[NT];  // 16 KB: scatter accumulator
  __shared__ float rtmp[16];
  __shared__ float rmax, rinv;
  const int b = blockIdx.x;
  const int tid = threadIdx.x;
  const int wid = tid >> 6, lane = tid & 63;

  float s[4];
  float mx = -1e30f;
#pragma unroll
  for (int p = 0; p < 4; ++p) {
    s[p] = sc[b * NT + tid + p * 1024];
    mx = fmaxf(mx, s[p]);
  }
#pragma unroll
  for (int d = 32; d >= 1; d >>= 1) mx = fmaxf(mx, __shfl_xor(mx, d, 64));
  if (lane == 0) rtmp[wid] = mx;
  __syncthreads();
  if (tid == 0) {
    float mm = rtmp[0];
#pragma unroll
    for (int i = 1; i < 16; ++i) mm = fmaxf(mm, rtmp[i]);
    rmax = mm;
  }
  __syncthreads();
  mx = rmax;
  float e[4];
  float sm = 0.f;
#pragma unroll
  for (int p = 0; p < 4; ++p) {
    e[p] = __expf(s[p] - mx);
    sm += e[p];
  }
#pragma unroll
  for (int d = 32; d >= 1; d >>= 1) sm += __shfl_xor(sm, d, 64);
  if (lane == 0) rtmp[wid] = sm;
  __syncthreads();
  if (tid == 0) {
    float tt = 0.f;
#pragma unroll
    for (int i = 0; i < 16; ++i) tt += rtmp[i];
    rinv = 0.1f / tt;
  }
  __syncthreads();
  const float inv = rinv;
#pragma unroll
  for (int p = 0; p < 4; ++p) {
    wls[tid + p * 1024] = e[p] * inv;
    accs[tid + p * 1024] = 0.f;
  }
  __syncthreads();
#pragma unroll
  for (int i = 0; i < 8; ++i) {
    const int eid = b * NE + tid + i * 1024;
    const int ss = esrc[eid];
    const int dd = edst[eid];
    const float wv = wls[ss];
    if (dd != ss + 1) atomicAdd(&accs[dd], wv);
  }
  __syncthreads();
#pragma unroll
  for (int p = 0; p < 4; ++p)
    out[b * NT + tid + p * 1024] = accs[tid + p * 1024];
}

extern "C" void kernel_launch(void* const* d_in, const int* in_sizes, int n_in,
                              void* d_out, int out_size, void* d_ws, size_t ws_size,
                              hipStream_t stream) {
  const float* hidden = (const float*)d_in[0];
  const float* enc    = (const float*)d_in[1];
  const int*   esrc   = (const int*)d_in[2];
  const int*   edst   = (const int*)d_in[3];
  const float* Wattn  = (const float*)d_in[4];
  const float* battn  = (const float*)d_in[5];
  const float* vvec   = (const float*)d_in[6];
  float* out = (float*)d_out;

  char* ws = (char*)d_ws;
  float* cvecT  = (float*)ws;                    // 512*32*4   = 64 KB
  short* WbfT   = (short*)(ws + 65536);          // 512*256*2  = 256 KB
  float* scores = (float*)(ws + 65536 + 262144); // 32*4096*4  = 512 KB

  // probe first: its only (value-guarded, ~never-taken) writes hit scores,
  // which the real score_gemm fully overwrites below.
  probe_noA8<<<(NB * NT) / 128, 1024, 0, stream>>>(WbfT, cvecT, vvec, scores);
  prep<<<384, 256, 0, stream>>>(hidden, Wattn, battn, cvecT, WbfT);
  score_gemm<<<(NB * NT) / 128, 1024, 0, stream>>>(enc, WbfT, cvecT, vvec, scores);
  softmax_scatter<<<NB, 1024, 0, stream>>>(scores, esrc, edst, out);
}

// Round 6
// 348.850 us; speedup vs baseline: 2.4966x; 2.4966x over previous
//
#include <hip/hip_runtime.h>
#include <hip/hip_bf16.h>
#include <hip/hip_cooperative_groups.h>

namespace cg = cooperative_groups;

typedef __attribute__((ext_vector_type(8))) short bf16x8;
typedef __attribute__((ext_vector_type(4))) float f32x4;

#define HD 256   // hidden size (K of the big GEMM)
#define NB 32    // batch
#define NT 4096  // timesteps
#define NE 8192  // edges per graph
#define N2 512   // 2*H (N of the big GEMM)

static __device__ __forceinline__ unsigned short f2bf(float f) {
  unsigned int u = __float_as_uint(f);
  u += 0x7fff + ((u >> 16) & 1);  // round-to-nearest-even
  return (unsigned short)(u >> 16);
}
static __device__ __forceinline__ short4 cvt4(float4 a) {
  return make_short4((short)f2bf(a.x), (short)f2bf(a.y),
                     (short)f2bf(a.z), (short)f2bf(a.w));
}
// tanh(x) = 1 - 2/(e^{2x}+1); e^{2x} via exp2. Saturates correctly at +-inf.
static __device__ __forceinline__ float fast_tanh(float x) {
  float e = __builtin_amdgcn_exp2f(x * 2.8853900817779268f);  // 2/ln2
  return __builtin_fmaf(-2.f, __builtin_amdgcn_rcpf(e + 1.f), 1.f);
}
// pack 8 fp32 (k-ascending) -> bf16x8 by truncation (validated R9)
static __device__ __forceinline__ bf16x8 pack8(float4 a, float4 b) {
  union { bf16x8 v; unsigned int u[4]; } r;
  r.u[0] = (__float_as_uint(a.y) & 0xffff0000u) | (__float_as_uint(a.x) >> 16);
  r.u[1] = (__float_as_uint(a.w) & 0xffff0000u) | (__float_as_uint(a.z) >> 16);
  r.u[2] = (__float_as_uint(b.y) & 0xffff0000u) | (__float_as_uint(b.x) >> 16);
  r.u[3] = (__float_as_uint(b.w) & 0xffff0000u) | (__float_as_uint(b.z) >> 16);
  return r.v;
}

// Load one K-step's B fragments (4 x bf16x8). Coalesced: for fixed (kk,nf)
// the wave's 64 lanes cover one CONTIGUOUS 1KB run of WbfT.
static __device__ __forceinline__ void bload(bf16x8* dst, const short* __restrict__ Wp,
                                             int nbase, int q, int kk) {
  const short* base = Wp + (kk * 512 + nbase) * 32 + q * 8;
#pragma unroll
  for (int nf = 0; nf < 4; ++nf)
    dst[nf] = *(const bf16x8*)(base + nf * 16 * 32);
}

// One K-step (BK=32): 4 A-frag bf16 ds_reads + 16 MFMAs against held B frags.
static __device__ __forceinline__ void kstep(f32x4 acc[4][4], const short* Abf,
                                             const bf16x8* b, int m, int q, int ks) {
#pragma unroll
  for (int mi = 0; mi < 4; ++mi) {
    const int r = mi * 16 + m;
    const int cc = ks * 4 + q;
    const int slot = (cc & ~7) | ((cc & 7) ^ (r & 7));
    bf16x8 af = *(const bf16x8*)&Abf[r * 256 + slot * 8];
#pragma unroll
    for (int nf = 0; nf < 4; ++nf)
      acc[mi][nf] =
          __builtin_amdgcn_mfma_f32_16x16x32_bf16(af, b[nf], acc[mi][nf], 0, 0, 0);
  }
}

// ---------------------------------------------------------------------------
// ONE cooperative kernel: prep -> grid.sync -> GEMM(8 tiles/block, T14
// async-staged) -> grid.sync -> softmax+scatter. Removes 3 launch gaps (the
// ~163us end-to-end residual that 5 rounds of GEMM-side work never touched).
// Grid 256 x 512 thr: ~190 VGPR (2 waves/SIMD), ~66KB LDS -> 1 block/CU,
// grid == CU count, cooperative-capacity safe.
// ---------------------------------------------------------------------------
__global__ __launch_bounds__(512, 2) void fused(
    const float* __restrict__ hidden, const float* __restrict__ enc,
    const int* __restrict__ esrc, const int* __restrict__ edst,
    const float* __restrict__ Wattn, const float* __restrict__ battn,
    const float* __restrict__ vvec, float* __restrict__ cvecT,
    short* __restrict__ WbfT, float* __restrict__ scores,
    float* __restrict__ out) {
  cg::grid_group grid = cg::this_grid();
  const int tid = threadIdx.x;
  const int bx = blockIdx.x;

  // ================= phase P: cvec + weight convert =================
  {
    // cvecT[n][b] = b_attn[n] + hidden[b].W_attn[n][0:256]; block bx owns
    // n = 2bx, 2bx+1. 8 threads per (n,b) dot, k-slice of 32 each.
    const int nn = tid >> 8;          // 0..1
    const int n = 2 * bx + nn;
    const int b = (tid >> 3) & 31;
    const int s = tid & 7;
    const float* wrow = Wattn + n * N2 + s * 32;
    const float* hrow = hidden + b * HD + s * 32;
    float sum = 0.f;
#pragma unroll
    for (int z = 0; z < 32; z += 4) {
      float4 w4 = *(const float4*)(wrow + z);
      float4 h4 = *(const float4*)(hrow + z);
      sum = fmaf(h4.x, w4.x, sum);
      sum = fmaf(h4.y, w4.y, sum);
      sum = fmaf(h4.z, w4.z, sum);
      sum = fmaf(h4.w, w4.w, sum);
    }
    sum += __shfl_xor(sum, 1, 64);
    sum += __shfl_xor(sum, 2, 64);
    sum += __shfl_xor(sum, 4, 64);
    if (s == 0) cvecT[n * NB + b] = sum + battn[n];
    // WbfT k-block-major convert: WbfT[((k>>5)*512+n)*32+(k&31)] = bf16(W2[n][k])
    if (tid < 128) {
      const int f = bx * 128 + tid;  // 0..32767 float4-chunks
      const int n2 = f >> 6, k4 = (f & 63) * 4;
      float4 w4 = *(const float4*)(Wattn + n2 * N2 + HD + k4);
      *(short4*)(WbfT + ((k4 >> 5) * 512 + n2) * 32 + (k4 & 31)) = cvt4(w4);
    }
  }
  grid.sync();

  // ================= phase G: 8 x (64M x 512N) tiles =================
  __shared__ short Abf[64 * 256];  // 64 rows x 256 k bf16, swizzled: 32 KB
  __shared__ float part[8][64];
  const int w = tid >> 6, lane = tid & 63, q = lane >> 4, m = lane & 15;
  const int nbase = w * 64 + m;

  // tile-invariant epilogue operands hoisted to registers (epilogue becomes
  // pure VALU/trans; keeps the vmcnt queue = {B, prefetch} only)
  f32x4 cvA[4], cvB[4];
  float vv[4];
#pragma unroll
  for (int nf = 0; nf < 4; ++nf) {
    const int n = w * 64 + nf * 16 + m;
    cvA[nf] = *(const f32x4*)(cvecT + n * NB + 4 * q);
    cvB[nf] = *(const f32x4*)(cvecT + n * NB + 16 + 4 * q);
    vv[nf] = vvec[n];
  }

  float4 pa[4], pb[4];  // T14 in-flight A tile (32 VGPR)
  {
    const int row0 = bx * 8 * 64;
#pragma unroll
    for (int i = 0; i < 4; ++i) {
      const int gg = i * 512 + tid, r = gg >> 5, c = gg & 31;
      const float* src = enc + (row0 + r) * HD + c * 8;
      pa[i] = *(const float4*)src;
      pb[i] = *(const float4*)(src + 4);
    }
  }

#pragma unroll 1
  for (int tt = 0; tt < 8; ++tt) {
    const int row0 = (bx * 8 + tt) * 64;
    // ---- stage from in-flight regs: fp32 -> bf16, XOR-swizzled chunks ----
#pragma unroll
    for (int i = 0; i < 4; ++i) {
      const int gg = i * 512 + tid, r = gg >> 5, c = gg & 31;
      const int slot = (c & ~7) | ((c & 7) ^ (r & 7));
      *(bf16x8*)&Abf[r * 256 + slot * 8] = pack8(pa[i], pb[i]);
    }
    __syncthreads();

    f32x4 acc[4][4];
#pragma unroll
    for (int mi = 0; mi < 4; ++mi)
#pragma unroll
      for (int nf = 0; nf < 4; ++nf) acc[mi][nf] = (f32x4){0.f, 0.f, 0.f, 0.f};

    bf16x8 b0[4], b1[4];
    bload(b0, WbfT, nbase, q, 0);
#pragma unroll
    for (int ks2 = 0; ks2 < 4; ++ks2) {
      const int ks = ks2 * 2;
      bload(b1, WbfT, nbase, q, ks + 1);
      kstep(acc, Abf, b0, m, q, ks);
      if (ks2 < 3) bload(b0, WbfT, nbase, q, ks + 2);
      if (ks2 == 3 && tt < 7) {
        // T14: issue next tile's A loads AFTER the last B load -> B waits
        // never drain them; latency hides under last kstep + tanh epilogue.
        const int nr0 = row0 + 64;
#pragma unroll
        for (int i = 0; i < 4; ++i) {
          const int gg = i * 512 + tid, r = gg >> 5, c = gg & 31;
          const float* src = enc + (nr0 + r) * HD + c * 8;
          pa[i] = *(const float4*)src;
          pb[i] = *(const float4*)(src + 4);
        }
      }
      kstep(acc, Abf, b1, m, q, ks + 1);
    }

    // ---- epilogue: tanh + v-dot (no memory ops), reduce 64 cols ----
    float pr[4][4];
#pragma unroll
    for (int mi = 0; mi < 4; ++mi)
#pragma unroll
      for (int j = 0; j < 4; ++j) pr[mi][j] = 0.f;
#pragma unroll
    for (int nf = 0; nf < 4; ++nf) {
#pragma unroll
      for (int mi = 0; mi < 4; ++mi) {
        const f32x4 cv = (mi & 1) ? cvB[nf] : cvA[nf];
#pragma unroll
        for (int j = 0; j < 4; ++j)
          pr[mi][j] += fast_tanh(acc[mi][nf][j] + cv[j]) * vv[nf];
      }
    }
#pragma unroll
    for (int mi = 0; mi < 4; ++mi) {
#pragma unroll
      for (int j = 0; j < 4; ++j) {
        float e = pr[mi][j];
        e += __shfl_xor(e, 1, 64);
        e += __shfl_xor(e, 2, 64);
        e += __shfl_xor(e, 4, 64);
        e += __shfl_xor(e, 8, 64);  // sum over the 16 m-lanes
        if (m == 0) part[w][mi * 16 + 4 * q + j] = e;
      }
    }
    __syncthreads();
    if (tid < 64) {
      const int r = row0 + tid;  // flat row = t*NB + b
      float s = 0.f;
#pragma unroll
      for (int ww = 0; ww < 8; ++ww) s += part[ww][tid];
      scores[(r & 31) * NT + (r >> 5)] = s;
    }
    // no extra barrier: next stage writes Abf (disjoint from part); the
    // post-stage __syncthreads orders everything.
  }
  grid.sync();

  // ================= phase S: softmax + edge scatter (32 blocks) =========
  if (bx < NB) {
    __shared__ float wls[NT];   // 16 KB: 0.1 * softmax(sc[b])
    __shared__ float accs[NT];  // 16 KB: scatter accumulator
    __shared__ float rtmp[8];
    __shared__ float rmax, rinv;
    const int b = bx;
    const int wid = tid >> 6;

    float s[8];
    float mx = -1e30f;
#pragma unroll
    for (int p = 0; p < 8; ++p) {
      s[p] = scores[b * NT + tid + p * 512];
      mx = fmaxf(mx, s[p]);
    }
#pragma unroll
    for (int d = 32; d >= 1; d >>= 1) mx = fmaxf(mx, __shfl_xor(mx, d, 64));
    if ((tid & 63) == 0) rtmp[wid] = mx;
    __syncthreads();
    if (tid == 0) {
      float mm = rtmp[0];
#pragma unroll
      for (int i = 1; i < 8; ++i) mm = fmaxf(mm, rtmp[i]);
      rmax = mm;
    }
    __syncthreads();
    mx = rmax;
    float e[8];
    float sm = 0.f;
#pragma unroll
    for (int p = 0; p < 8; ++p) {
      e[p] = __expf(s[p] - mx);
      sm += e[p];
    }
#pragma unroll
    for (int d = 32; d >= 1; d >>= 1) sm += __shfl_xor(sm, d, 64);
    if ((tid & 63) == 0) rtmp[wid] = sm;
    __syncthreads();
    if (tid == 0) {
      float tt = 0.f;
#pragma unroll
      for (int i = 0; i < 8; ++i) tt += rtmp[i];
      rinv = 0.1f / tt;
    }
    __syncthreads();
    const float inv = rinv;
#pragma unroll
    for (int p = 0; p < 8; ++p) {
      wls[tid + p * 512] = e[p] * inv;
      accs[tid + p * 512] = 0.f;
    }
    __syncthreads();
#pragma unroll
    for (int i = 0; i < 16; ++i) {
      const int eid = b * NE + tid + i * 512;
      const int ss = esrc[eid];
      const int dd = edst[eid];
      const float wv = wls[ss];
      if (dd != ss + 1) atomicAdd(&accs[dd], wv);
    }
    __syncthreads();
#pragma unroll
    for (int p = 0; p < 8; ++p)
      out[b * NT + tid + p * 512] = accs[tid + p * 512];
  }
}

extern "C" void kernel_launch(void* const* d_in, const int* in_sizes, int n_in,
                              void* d_out, int out_size, void* d_ws, size_t ws_size,
                              hipStream_t stream) {
  const float* hidden = (const float*)d_in[0];
  const float* enc    = (const float*)d_in[1];
  const int*   esrc   = (const int*)d_in[2];
  const int*   edst   = (const int*)d_in[3];
  const float* Wattn  = (const float*)d_in[4];
  const float* battn  = (const float*)d_in[5];
  const float* vvec   = (const float*)d_in[6];
  float* out = (float*)d_out;

  char* ws = (char*)d_ws;
  float* cvecT  = (float*)ws;                    // 512*32*4   = 64 KB
  short* WbfT   = (short*)(ws + 65536);          // 512*256*2  = 256 KB
  float* scores = (float*)(ws + 65536 + 262144); // 32*4096*4  = 512 KB

  void* args[] = {&hidden, &enc, &esrc, &edst, &Wattn, &battn, &vvec,
                  &cvecT, &WbfT, &scores, &out};
  hipLaunchCooperativeKernel((const void*)fused, dim3(256), dim3(512), args, 0,
                             stream);
}

// Round 7
// 278.419 us; speedup vs baseline: 3.1281x; 1.2530x over previous
//
#include <hip/hip_runtime.h>
#include <hip/hip_bf16.h>

typedef __attribute__((ext_vector_type(8))) short bf16x8;
typedef __attribute__((ext_vector_type(4))) float f32x4;

#define HD 256   // hidden size (K of the big GEMM)
#define NB 32    // batch
#define NT 4096  // timesteps
#define NE 8192  // edges per graph
#define N2 512   // 2*H (N of the big GEMM)

static __device__ __forceinline__ unsigned short f2bf(float f) {
  unsigned int u = __float_as_uint(f);
  u += 0x7fff + ((u >> 16) & 1);  // round-to-nearest-even
  return (unsigned short)(u >> 16);
}
static __device__ __forceinline__ short4 cvt4(float4 a) {
  return make_short4((short)f2bf(a.x), (short)f2bf(a.y),
                     (short)f2bf(a.z), (short)f2bf(a.w));
}
// tanh(x) = 1 - 2/(e^{2x}+1); e^{2x} via exp2. Saturates correctly at +-inf.
static __device__ __forceinline__ float fast_tanh(float x) {
  float e = __builtin_amdgcn_exp2f(x * 2.8853900817779268f);  // 2/ln2
  return __builtin_fmaf(-2.f, __builtin_amdgcn_rcpf(e + 1.f), 1.f);
}
// pack 8 fp32 (k-ascending) -> bf16x8 by truncation (validated R9)
static __device__ __forceinline__ bf16x8 pack8(float4 a, float4 b) {
  union { bf16x8 v; unsigned int u[4]; } r;
  r.u[0] = (__float_as_uint(a.y) & 0xffff0000u) | (__float_as_uint(a.x) >> 16);
  r.u[1] = (__float_as_uint(a.w) & 0xffff0000u) | (__float_as_uint(a.z) >> 16);
  r.u[2] = (__float_as_uint(b.y) & 0xffff0000u) | (__float_as_uint(b.x) >> 16);
  r.u[3] = (__float_as_uint(b.w) & 0xffff0000u) | (__float_as_uint(b.z) >> 16);
  return r.v;
}

// Fused prep:
//  blocks 0..255   : cvecT[n][b] = b_attn[n] + hidden[b] . W_attn[n][0:256]
//  blocks 256..383 : WbfT k-block-major bf16 convert of W_attn[n][256+k]:
//                    WbfT[((k>>5)*512 + n)*32 + (k&31)] = bf16(W2[n][k])
__global__ __launch_bounds__(256) void prep(
    const float* __restrict__ hidden, const float* __restrict__ Wattn,
    const float* __restrict__ battn, float* __restrict__ cvecT,
    short* __restrict__ WbfT) {
  const int tid = threadIdx.x;
  if (blockIdx.x < 256) {
    __shared__ float Ws[64 * 260];
    __shared__ float Hs[HD];
    const int chunk = blockIdx.x & 7;
    const int b = blockIdx.x >> 3;
#pragma unroll
    for (int it = 0; it < 16; ++it) {
      int f = it * 1024 + tid * 4;
      int i = f >> 8, k = f & 255;
      float4 w4 = *(const float4*)(Wattn + (chunk * 64 + i) * N2 + k);
      *(float4*)&Ws[i * 260 + k] = w4;
    }
    if (tid < 64)
      *(float4*)&Hs[tid * 4] = *(const float4*)(hidden + b * HD + tid * 4);
    __syncthreads();
    const int nl = tid >> 2;
    const int kb = (tid & 3) * 64;
    float sum = 0.f;
#pragma unroll
    for (int z = 0; z < 64; z += 4) {
      float4 h4 = *(const float4*)&Hs[kb + z];
      float4 w4 = *(const float4*)&Ws[nl * 260 + kb + z];
      sum = fmaf(h4.x, w4.x, sum);
      sum = fmaf(h4.y, w4.y, sum);
      sum = fmaf(h4.z, w4.z, sum);
      sum = fmaf(h4.w, w4.w, sum);
    }
    sum += __shfl_xor(sum, 1, 64);
    sum += __shfl_xor(sum, 2, 64);
    if ((tid & 3) == 0)
      cvecT[(chunk * 64 + nl) * NB + b] = sum + battn[chunk * 64 + nl];
  } else {
    int f = (blockIdx.x - 256) * 1024 + tid * 4;  // 0..131071 = n*256+k
    int n = f >> 8, k = f & 255;                  // k multiple of 4
    float4 w4 = *(const float4*)(Wattn + n * N2 + HD + k);
    *(short4*)(WbfT + ((k >> 5) * 512 + n) * 32 + (k & 31)) = cvt4(w4);
  }
}

// Load one K-step's B fragments (4 x bf16x8). Coalesced: for fixed (kk,nf)
// the wave's 64 lanes cover one CONTIGUOUS 1KB run of WbfT.
static __device__ __forceinline__ void bload(bf16x8* dst, const short* __restrict__ Wp,
                                             int nbase, int q, int kk) {
  const short* base = Wp + (kk * 512 + nbase) * 32 + q * 8;
#pragma unroll
  for (int nf = 0; nf < 4; ++nf)
    dst[nf] = *(const bf16x8*)(base + nf * 16 * 32);
}

// One K-step (BK=32): 4 A-frag bf16 ds_reads + 16 MFMAs against held B frags.
static __device__ __forceinline__ void kstep(f32x4 acc[4][4], const short* Abf,
                                             const bf16x8* b, int rb, int m, int q,
                                             int ks) {
#pragma unroll
  for (int mi = 0; mi < 4; ++mi) {
    const int r = rb + mi * 16 + m;
    const int cc = ks * 4 + q;
    const int slot = (cc & ~7) | ((cc & 7) ^ (r & 7));
    bf16x8 af = *(const bf16x8*)&Abf[r * 256 + slot * 8];
#pragma unroll
    for (int nf = 0; nf < 4; ++nf)
      acc[mi][nf] =
          __builtin_amdgcn_mfma_f32_16x16x32_bf16(af, b[nf], acc[mi][nf], 0, 0, 0);
  }
}

// B-coalesced, M128 GEMM (R3 body) with LDS trimmed to EXACTLY 64 KB:
// part[16][64] is aliased onto the first 4 KB of Abf (a barrier separates the
// last Abf ds_read from the first part write, so the alias is race-free).
// 2 x 65536 = 131072 B -> TWO blocks co-resident per CU. Independent blocks
// sit in different phases (one in K-loop MFMA/DS while the other runs the
// tanh/trans epilogue), overlapping the pipes that R0-R5 executed serially
// (probe R5: pipe-busy sum ~= 80us == no-enc floor -> zero overlap before).
__global__ __launch_bounds__(1024, 4) void score_gemm(
    const float* __restrict__ enc, const short* __restrict__ WbfT,
    const float* __restrict__ cvecT, const float* __restrict__ vvec,
    float* __restrict__ scores) {
  __shared__ short Abf[128 * 256];  // 64 KB total; first 4 KB reused as part[][]
  float(*part)[64] = (float(*)[64])Abf;
  const int tid = threadIdx.x;
  const int w = tid >> 6, lane = tid & 63, q = lane >> 4, m = lane & 15;
  const int g = w >> 3, wl = w & 7;
  const int row0 = blockIdx.x * 128;

  // ---- stage ALL of A: fp32 global -> bf16 LDS (each thread 4 chunks) ----
#pragma unroll
  for (int i = 0; i < 4; ++i) {
    const int gg = i * 1024 + tid;     // 0..4095 = r*32 + c
    const int r = gg >> 5, c = gg & 31;
    const float* src = enc + (row0 + r) * HD + c * 8;
    float4 a0 = *(const float4*)src;
    float4 a1 = *(const float4*)(src + 4);
    const int slot = (c & ~7) | ((c & 7) ^ (r & 7));
    *(bf16x8*)&Abf[r * 256 + slot * 8] = pack8(a0, a1);
  }

  f32x4 acc[4][4];
#pragma unroll
  for (int mi = 0; mi < 4; ++mi)
#pragma unroll
    for (int nf = 0; nf < 4; ++nf) acc[mi][nf] = (f32x4){0.f, 0.f, 0.f, 0.f};

  const int nbase = wl * 64 + m;
  const int rb = g * 64;
  bf16x8 b0[4], b1[4];
  bload(b0, WbfT, nbase, q, 0);  // prologue B prefetch

  __syncthreads();  // A staged, everyone may read LDS

#pragma unroll 1
  for (int ks2 = 0; ks2 < 4; ++ks2) {
    const int ks = ks2 * 2;
    bload(b1, WbfT, nbase, q, ks + 1);  // prefetch next step's B
    kstep(acc, Abf, b0, rb, m, q, ks);
    if (ks2 < 3) bload(b0, WbfT, nbase, q, ks + 2);
    kstep(acc, Abf, b1, rb, m, q, ks + 1);
  }

  // ---- epilogue: tanh + v-dot in registers (no LDS traffic) ----
  float p[4][4];
#pragma unroll
  for (int mi = 0; mi < 4; ++mi)
#pragma unroll
    for (int j = 0; j < 4; ++j) p[mi][j] = 0.f;

#pragma unroll
  for (int nf = 0; nf < 4; ++nf) {
    const int n = wl * 64 + nf * 16 + m;
    const float vv = vvec[n];
    // C/D layout: M-coord = rb + mi*16 + 4q+j; b-index = (mi*16+4q+j)&31
    const f32x4 cvA = *(const f32x4*)(cvecT + n * NB + 4 * q);        // mi even
    const f32x4 cvB = *(const f32x4*)(cvecT + n * NB + 16 + 4 * q);   // mi odd
#pragma unroll
    for (int mi = 0; mi < 4; ++mi) {
      const f32x4 cv = (mi & 1) ? cvB : cvA;
#pragma unroll
      for (int j = 0; j < 4; ++j)
        p[mi][j] += fast_tanh(acc[mi][nf][j] + cv[j]) * vv;
    }
  }

  __syncthreads();  // ALL Abf ds_reads done -> safe to write aliased part[]

#pragma unroll
  for (int mi = 0; mi < 4; ++mi) {
#pragma unroll
    for (int j = 0; j < 4; ++j) {
      float e = p[mi][j];
      e += __shfl_xor(e, 1, 64);
      e += __shfl_xor(e, 2, 64);
      e += __shfl_xor(e, 4, 64);
      e += __shfl_xor(e, 8, 64);  // sum over the 16 m-lanes
      if (m == 0) part[w][mi * 16 + 4 * q + j] = e;
    }
  }
  __syncthreads();
  if (tid < 128) {
    const int r = row0 + tid;  // flat row = t*NB + b
    float s = 0.f;
#pragma unroll
    for (int ww = 0; ww < 8; ++ww) s += part[(tid >> 6) * 8 + ww][tid & 63];
    scores[(r & 31) * NT + (r >> 5)] = s;
  }
}

// Fused softmax + edge scatter: one block per batch b (1024 threads).
// Softmax weights (0.1*softmax) AND the output accumulator live in LDS;
// edges do LDS atomics instead of 262K device-scope L2 atomics;
// out is written once, coalesced (no separate zeroing pass).
__global__ __launch_bounds__(1024) void softmax_scatter(
    const float* __restrict__ sc, const int* __restrict__ esrc,
    const int* __restrict__ edst, float* __restrict__ out) {
  __shared__ float wls[NT];   // 16 KB: 0.1 * softmax(sc[b])
  __shared__ float accs[NT];  // 16 KB: scatter accumulator
  __shared__ float rtmp[16];
  __shared__ float rmax, rinv;
  const int b = blockIdx.x;
  const int tid = threadIdx.x;
  const int wid = tid >> 6, lane = tid & 63;

  float s[4];
  float mx = -1e30f;
#pragma unroll
  for (int p = 0; p < 4; ++p) {
    s[p] = sc[b * NT + tid + p * 1024];
    mx = fmaxf(mx, s[p]);
  }
#pragma unroll
  for (int d = 32; d >= 1; d >>= 1) mx = fmaxf(mx, __shfl_xor(mx, d, 64));
  if (lane == 0) rtmp[wid] = mx;
  __syncthreads();
  if (tid == 0) {
    float mm = rtmp[0];
#pragma unroll
    for (int i = 1; i < 16; ++i) mm = fmaxf(mm, rtmp[i]);
    rmax = mm;
  }
  __syncthreads();
  mx = rmax;
  float e[4];
  float sm = 0.f;
#pragma unroll
  for (int p = 0; p < 4; ++p) {
    e[p] = __expf(s[p] - mx);
    sm += e[p];
  }
#pragma unroll
  for (int d = 32; d >= 1; d >>= 1) sm += __shfl_xor(sm, d, 64);
  if (lane == 0) rtmp[wid] = sm;
  __syncthreads();
  if (tid == 0) {
    float tt = 0.f;
#pragma unroll
    for (int i = 0; i < 16; ++i) tt += rtmp[i];
    rinv = 0.1f / tt;
  }
  __syncthreads();
  const float inv = rinv;
#pragma unroll
  for (int p = 0; p < 4; ++p) {
    wls[tid + p * 1024] = e[p] * inv;
    accs[tid + p * 1024] = 0.f;
  }
  __syncthreads();
#pragma unroll
  for (int i = 0; i < 8; ++i) {
    const int eid = b * NE + tid + i * 1024;
    const int ss = esrc[eid];
    const int dd = edst[eid];
    const float wv = wls[ss];
    if (dd != ss + 1) atomicAdd(&accs[dd], wv);
  }
  __syncthreads();
#pragma unroll
  for (int p = 0; p < 4; ++p)
    out[b * NT + tid + p * 1024] = accs[tid + p * 1024];
}

extern "C" void kernel_launch(void* const* d_in, const int* in_sizes, int n_in,
                              void* d_out, int out_size, void* d_ws, size_t ws_size,
                              hipStream_t stream) {
  const float* hidden = (const float*)d_in[0];
  const float* enc    = (const float*)d_in[1];
  const int*   esrc   = (const int*)d_in[2];
  const int*   edst   = (const int*)d_in[3];
  const float* Wattn  = (const float*)d_in[4];
  const float* battn  = (const float*)d_in[5];
  const float* vvec   = (const float*)d_in[6];
  float* out = (float*)d_out;

  char* ws = (char*)d_ws;
  float* cvecT  = (float*)ws;                    // 512*32*4   = 64 KB
  short* WbfT   = (short*)(ws + 65536);          // 512*256*2  = 256 KB
  float* scores = (float*)(ws + 65536 + 262144); // 32*4096*4  = 512 KB

  prep<<<384, 256, 0, stream>>>(hidden, Wattn, battn, cvecT, WbfT);
  score_gemm<<<(NB * NT) / 128, 1024, 0, stream>>>(enc, WbfT, cvecT, vvec, scores);
  softmax_scatter<<<NB, 1024, 0, stream>>>(scores, esrc, edst, out);
}